// Round 3
// baseline (167.688 us; speedup 1.0000x reference)
//
#include <hip/hip_runtime.h>
#include <hip/hip_bf16.h>
#include <math.h>

// ---------------------------------------------------------------------------
// SCF_GRUCell: spatial binning of 400k neighbors -> segment mean (64 bins x 48)
// -> FC(48x3072)+ReLU -> scalar-gate GRU (rt is dead code in the reference).
//
// Round 3: cooperative bin_accum. Per 64-item chunk: lane l computes item
// (i0+l)'s bin from loc (coalesced float2), packs (bin<<20)|index. Then 16
// steps x 4 items: lanes (g=lane/16, q=lane%16); q<12 read the hiddens row as
// coalesced float4 (addresses via register shfl -> no dependent chain, loads
// pipeline deeply) and ds_add into s_sum[bin*49 + q*4+c]; q==12 adds count
// into free column 48. Masked items -> dummy row 64. 5 DS atomics / 4 items
// (was 196), zero divergence in the steady state.
//
// ws layout (floats):
//   [0, 3136)    : combined [64][49] (col 48 = count)
//   [3136, 3184) : fsp [48]
//   [3200, ...)  : per-block partials, P slots x SLOT floats
// ---------------------------------------------------------------------------

#define NBINS 64
#define ROWS 65       // 64 bins + dummy row for masked/OOB
#define PAD 49        // row stride; column 48 holds the count
#define ENT 3136      // 64*49 entries (sums + counts)
#define SLOT 3200     // padded partial slot stride (floats)
#define PART_OFF 3200
#define FSP_OFF 3136

__global__ void zero_partials_kernel(float* part, int total) {
    int i = blockIdx.x * blockDim.x + threadIdx.x;
    if (i < total) part[i] = 0.0f;
}

__global__ __launch_bounds__(1024) void bin_accum_kernel(
    const float2* __restrict__ loc_others,
    const float*  __restrict__ loc_agent,
    const int*    __restrict__ loc_other_index,
    const float*  __restrict__ hiddens,
    float* __restrict__ part,      // [P][SLOT]
    int n, int P, int direct)
{
    __shared__ float s_sum[ROWS * PAD];   // 3185 floats = 12.7 KB
    for (int k = threadIdx.x; k < ROWS * PAD; k += 1024) s_sum[k] = 0.0f;
    __syncthreads();

    const float ax = loc_agent[0];
    const float ay = loc_agent[1];

    const int lane = threadIdx.x & 63;
    const int g = lane >> 4;        // item subgroup 0..3 within a step
    const int q = lane & 15;        // role within subgroup
    const int wave = (blockIdx.x * 1024 + threadIdx.x) >> 6;
    const int nwaves = (gridDim.x * 1024) >> 6;
    const int nchunks = (n + 63) >> 6;

    for (int c = wave; c < nchunks; c += nwaves) {
        int i = c * 64 + lane;
        int pk;
        if (i < n) {
            float2 p = loc_others[i];
            float cx = p.x - ax;
            float cy = p.y - ay;
            float d = sqrtf(cx * cx + cy * cy);
            int bin = NBINS;  // dummy
            if (d >= 0.5f && d <= 40.0f) {
                float ac = acosf(fminf(fmaxf(cx / d, -1.0f), 1.0f));
                float theta = (cy < 0.0f) ? (6.283185307179586f - ac) : ac;
                float uf = floorf((d - 0.5f) / 4.9375f);           // RADIUS_STEP
                float vf = floorf(theta / 0.7853981633974483f);    // THETA_STEP
                int u = (int)fminf(fmaxf(uf, 0.0f), 7.0f);
                int v = (int)fminf(fmaxf(vf, 0.0f), 7.0f);
                bin = u * 8 + v;
            }
            pk = (bin << 20) | loc_other_index[i];
        } else {
            pk = (NBINS << 20);
        }

#pragma unroll
        for (int s = 0; s < 16; ++s) {
            int pkg = __shfl(pk, s * 4 + g, 64);
            int bin = pkg >> 20;
            int row = pkg & 0xFFFFF;
            if (q < 12) {
                const float4 h = *(const float4*)(hiddens + (size_t)row * 48 + q * 4);
                float* dst = s_sum + bin * PAD + q * 4;
                unsafeAtomicAdd(dst + 0, h.x);
                unsafeAtomicAdd(dst + 1, h.y);
                unsafeAtomicAdd(dst + 2, h.z);
                unsafeAtomicAdd(dst + 3, h.w);
            } else if (q == 12) {
                unsafeAtomicAdd(&s_sum[bin * PAD + 48], 1.0f);  // dummy row absorbs masked
            }
        }
    }
    __syncthreads();

    // Epilogue: private histogram -> this block's slot (plain coalesced stores).
    float* dst = part + (size_t)(blockIdx.x % P) * SLOT;
    if (direct) {
        for (int k = threadIdx.x; k < ENT; k += 1024) dst[k] = s_sum[k];
    } else {
        for (int k = threadIdx.x; k < ENT; k += 1024) unsafeAtomicAdd(&dst[k], s_sum[k]);
    }
}

__global__ __launch_bounds__(256) void combine_kernel(
    float* __restrict__ ws,          // combined area, [0, ENT)
    const float* __restrict__ part,  // [P][SLOT]
    int P)
{
    int k = blockIdx.x * 256 + threadIdx.x;
    if (k >= ENT) return;
    float s = 0.0f;
#pragma unroll 8
    for (int b = 0; b < P; ++b) s += part[(size_t)b * SLOT + k];
    ws[k] = s;
}

__global__ __launch_bounds__(256) void fc_kernel(
    const float* __restrict__ W_fc,    // [48][3072]
    const float* __restrict__ b_fc,    // [48]
    const float* __restrict__ comb,    // ws [64][49]
    float* __restrict__ fsp)           // ws[3136..3183]
{
    int r = blockIdx.x;
    const float* w = W_fc + (size_t)r * (NBINS * 48);
    float partial = 0.0f;
    for (int k = threadIdx.x; k < NBINS * 48; k += 256) {
        int b = k / 48;
        int j = k - b * 48;
        float c = comb[b * PAD + 48];
        float s = comb[b * PAD + j];
        float sp = (c > 1.0f) ? (s / c) : s;
        partial += w[k] * sp;
    }
    for (int off = 32; off >= 1; off >>= 1) partial += __shfl_down(partial, off, 64);
    __shared__ float red[4];
    if ((threadIdx.x & 63) == 0) red[threadIdx.x >> 6] = partial;
    __syncthreads();
    if (threadIdx.x == 0) {
        float s = red[0] + red[1] + red[2] + red[3];
        fsp[r] = fmaxf(s + b_fc[r], 0.0f);
    }
}

__global__ void gru_kernel(
    const float* __restrict__ feature_img,  // [1,32,80,80]
    const float* __restrict__ loc_agent,    // [2]
    const float* __restrict__ f_vel,        // [16]
    const float* __restrict__ fsp,          // [48] (ws)
    const float* __restrict__ hidden,       // [48]
    const float* __restrict__ w_iz, const float* __restrict__ w_hz,
    const float* __restrict__ b_iz, const float* __restrict__ b_hz,
    const float* __restrict__ w_in, const float* __restrict__ w_hn,
    const float* __restrict__ b_in, const float* __restrict__ b_hn,
    float* __restrict__ out)                // [48]
{
    int l = threadIdx.x;  // one wave
    int u0 = 40 - (int)loc_agent[1];
    int v0 = (int)loc_agent[0];
    int pix = u0 * 80 + v0;

    float pz = 0.0f, pn = 0.0f;
    for (int e = l; e < 96; e += 64) {
        float x;
        if (e < 32)      x = feature_img[e * 6400 + pix];
        else if (e < 48) x = f_vel[e - 32];
        else             x = fsp[e - 48];
        pz += x * w_iz[e];
        pn += x * w_in[e];
    }
    if (l < 48) {
        float h = hidden[l];
        pz += h * w_hz[l];
        pn += h * w_hn[l];
    }
    for (int off = 32; off >= 1; off >>= 1) {
        pz += __shfl_xor(pz, off, 64);
        pn += __shfl_xor(pn, off, 64);
    }
    float zt = 1.0f / (1.0f + expf(-(pz + b_iz[0] + b_hz[0])));
    float nt = tanhf(pn + b_in[0] + b_hn[0]);
    if (l < 48) out[l] = (1.0f - zt) * nt + zt * hidden[l];
}

extern "C" void kernel_launch(void* const* d_in, const int* in_sizes, int n_in,
                              void* d_out, int out_size, void* d_ws, size_t ws_size,
                              hipStream_t stream) {
    const float* loc_agent       = (const float*)d_in[0];
    const float* loc_others      = (const float*)d_in[1];
    const int*   loc_other_index = (const int*)d_in[2];
    const float* feature_img     = (const float*)d_in[3];
    const float* f_vel           = (const float*)d_in[4];
    const float* hiddens         = (const float*)d_in[5];
    const float* hidden          = (const float*)d_in[6];
    const float* W_fc            = (const float*)d_in[7];
    const float* b_fc            = (const float*)d_in[8];
    // d_in[9..12] = weight_ir / weight_hr / bias_ir / bias_hr : dead code
    const float* w_iz            = (const float*)d_in[13];
    const float* w_hz            = (const float*)d_in[14];
    const float* b_iz            = (const float*)d_in[15];
    const float* b_hz            = (const float*)d_in[16];
    const float* w_in            = (const float*)d_in[17];
    const float* w_hn            = (const float*)d_in[18];
    const float* b_in            = (const float*)d_in[19];
    const float* b_hn            = (const float*)d_in[20];

    float* ws   = (float*)d_ws;
    float* fsp  = ws + FSP_OFF;
    float* part = ws + PART_OFF;
    float* out  = (float*)d_out;

    int n = in_sizes[2];  // 400000 neighbors

    const int NBLK = 256;
    long wfloats = (long)(ws_size / 4);
    long avail = (wfloats - PART_OFF) / SLOT;
    int P = (int)(avail < 1 ? 1 : (avail > NBLK ? NBLK : avail));
    int direct = (P == NBLK) ? 1 : 0;

    if (!direct) {
        int total = P * SLOT;
        hipLaunchKernelGGL(zero_partials_kernel, dim3((total + 1023) / 1024),
                           dim3(1024), 0, stream, part, total);
    }
    hipLaunchKernelGGL(bin_accum_kernel, dim3(NBLK), dim3(1024), 0, stream,
                       (const float2*)loc_others, loc_agent, loc_other_index,
                       hiddens, part, n, P, direct);
    hipLaunchKernelGGL(combine_kernel, dim3((ENT + 255) / 256), dim3(256), 0, stream,
                       ws, part, P);
    hipLaunchKernelGGL(fc_kernel, dim3(48), dim3(256), 0, stream,
                       W_fc, b_fc, ws, fsp);
    hipLaunchKernelGGL(gru_kernel, dim3(1), dim3(64), 0, stream,
                       feature_img, loc_agent, f_vel, fsp, hidden,
                       w_iz, w_hz, b_iz, b_hz, w_in, w_hn, b_in, b_hn, out);
}

// Round 4
// 129.092 us; speedup vs baseline: 1.2990x; 1.2990x over previous
//
#include <hip/hip_runtime.h>
#include <hip/hip_bf16.h>
#include <math.h>
#include <stdint.h>

// ---------------------------------------------------------------------------
// SCF_GRUCell: spatial binning of 400k neighbors -> segment mean (64 bins x 48)
// -> FC(48x3072)+ReLU -> scalar-gate GRU (rt is dead code in the reference).
//
// Round 4: stream `hiddens` SEQUENTIALLY (float4/lane, fully coalesced) and
// invert the item->row indirection: K1 scatters each item's bin to
// binrow[index[i]] (1 byte), K2 streams hiddens flat and bins each float4 via
// binrow[row]. No gathers on the 76.8 MB array, no combine kernel (global
// atomic epilogue measured free in R1/R2).
//
// ws layout:
//   float [0, 3136)    : combined [64][49]  (col 48 = count)
//   float [3136, 3184) : fsp [48]
//   byte  [12800, ...) : binrow[n]  (uint8 bin per hiddens row; 64 = dummy)
// ---------------------------------------------------------------------------

#define NBINS 64
#define ROWS 65       // 64 bins + dummy row for masked / uncovered
#define PAD 49        // row stride; column 48 holds the count
#define ENT (NBINS * PAD)       // 3136
#define FSP_OFF ENT             // 3136
#define BINROW_OFF_B 12800      // byte offset of binrow in ws

__global__ __launch_bounds__(1024) void init_ws_kernel(
    float* __restrict__ ws, uint32_t* __restrict__ binrow32, int nwords)
{
    int i = blockIdx.x * 1024 + threadIdx.x;
    int stride = gridDim.x * 1024;
    for (int k = i; k < ENT + 64; k += stride) ws[k] = 0.0f;  // sums+cnts (+fsp ok)
    for (int k = i; k < nwords; k += stride) binrow32[k] = 0x40404040u;  // bin=64
}

__global__ __launch_bounds__(1024) void bin_kernel(
    const float2* __restrict__ loc_others,
    const float*  __restrict__ loc_agent,
    const int*    __restrict__ loc_other_index,
    uint8_t* __restrict__ binrow,
    float* __restrict__ ws,       // counts go to ws[b*49+48]
    int n)
{
    __shared__ float s_cnt[ROWS];
    if (threadIdx.x < ROWS) s_cnt[threadIdx.x] = 0.0f;
    __syncthreads();

    const float ax = loc_agent[0];
    const float ay = loc_agent[1];

    int i = blockIdx.x * 1024 + threadIdx.x;
    if (i < n) {
        float2 p = loc_others[i];
        float cx = p.x - ax;
        float cy = p.y - ay;
        float d = sqrtf(cx * cx + cy * cy);
        int bin = NBINS;  // dummy
        if (d >= 0.5f && d <= 40.0f) {
            float ac = acosf(fminf(fmaxf(cx / d, -1.0f), 1.0f));
            float theta = (cy < 0.0f) ? (6.283185307179586f - ac) : ac;
            float uf = floorf((d - 0.5f) / 4.9375f);           // RADIUS_STEP
            float vf = floorf(theta / 0.7853981633974483f);    // THETA_STEP
            int u = (int)fminf(fmaxf(uf, 0.0f), 7.0f);
            int v = (int)fminf(fmaxf(vf, 0.0f), 7.0f);
            bin = u * 8 + v;
        }
        binrow[loc_other_index[i]] = (uint8_t)bin;
        unsafeAtomicAdd(&s_cnt[bin], 1.0f);
    }
    __syncthreads();
    if (threadIdx.x < NBINS && s_cnt[threadIdx.x] != 0.0f)
        unsafeAtomicAdd(&ws[threadIdx.x * PAD + 48], s_cnt[threadIdx.x]);
}

__global__ __launch_bounds__(1024) void accum_kernel(
    const float4* __restrict__ hflat,     // hiddens as float4[n*12]
    const uint8_t* __restrict__ binrow,   // [n]
    float* __restrict__ ws,               // [64][49]
    int nf4)
{
    __shared__ float s_sum[ROWS * PAD];   // 3185 floats
    for (int k = threadIdx.x; k < ROWS * PAD; k += 1024) s_sum[k] = 0.0f;
    __syncthreads();

    int j = blockIdx.x * 1024 + threadIdx.x;
    int stride = gridDim.x * 1024;
    for (; j < nf4; j += stride) {
        unsigned row = (unsigned)j / 12u;
        unsigned phase = (unsigned)j - row * 12u;
        int b = binrow[row];
        float4 h = hflat[j];
        float* dst = s_sum + b * PAD + phase * 4;
        unsafeAtomicAdd(dst + 0, h.x);
        unsafeAtomicAdd(dst + 1, h.y);
        unsafeAtomicAdd(dst + 2, h.z);
        unsafeAtomicAdd(dst + 3, h.w);
    }
    __syncthreads();

    // Global combine: measured free in R1/R2 (pipelined L2 atomics).
    for (int k = threadIdx.x; k < ENT; k += 1024) {
        float v = s_sum[k];
        if (v != 0.0f) unsafeAtomicAdd(&ws[k], v);
    }
}

__global__ __launch_bounds__(256) void fc_kernel(
    const float* __restrict__ W_fc,    // [48][3072]
    const float* __restrict__ b_fc,    // [48]
    const float* __restrict__ comb,    // ws [64][49]
    float* __restrict__ fsp)           // ws[3136..3183]
{
    int r = blockIdx.x;
    const float* w = W_fc + (size_t)r * (NBINS * 48);
    float partial = 0.0f;
    for (int k = threadIdx.x; k < NBINS * 48; k += 256) {
        int b = k / 48;
        int jj = k - b * 48;
        float c = comb[b * PAD + 48];
        float s = comb[b * PAD + jj];
        float sp = (c > 1.0f) ? (s / c) : s;
        partial += w[k] * sp;
    }
    for (int off = 32; off >= 1; off >>= 1) partial += __shfl_down(partial, off, 64);
    __shared__ float red[4];
    if ((threadIdx.x & 63) == 0) red[threadIdx.x >> 6] = partial;
    __syncthreads();
    if (threadIdx.x == 0) {
        float s = red[0] + red[1] + red[2] + red[3];
        fsp[r] = fmaxf(s + b_fc[r], 0.0f);
    }
}

__global__ void gru_kernel(
    const float* __restrict__ feature_img,  // [1,32,80,80]
    const float* __restrict__ loc_agent,    // [2]
    const float* __restrict__ f_vel,        // [16]
    const float* __restrict__ fsp,          // [48] (ws)
    const float* __restrict__ hidden,       // [48]
    const float* __restrict__ w_iz, const float* __restrict__ w_hz,
    const float* __restrict__ b_iz, const float* __restrict__ b_hz,
    const float* __restrict__ w_in, const float* __restrict__ w_hn,
    const float* __restrict__ b_in, const float* __restrict__ b_hn,
    float* __restrict__ out)                // [48]
{
    int l = threadIdx.x;  // one wave
    int u0 = 40 - (int)loc_agent[1];
    int v0 = (int)loc_agent[0];
    int pix = u0 * 80 + v0;

    float pz = 0.0f, pn = 0.0f;
    for (int e = l; e < 96; e += 64) {
        float x;
        if (e < 32)      x = feature_img[e * 6400 + pix];
        else if (e < 48) x = f_vel[e - 32];
        else             x = fsp[e - 48];
        pz += x * w_iz[e];
        pn += x * w_in[e];
    }
    if (l < 48) {
        float h = hidden[l];
        pz += h * w_hz[l];
        pn += h * w_hn[l];
    }
    for (int off = 32; off >= 1; off >>= 1) {
        pz += __shfl_xor(pz, off, 64);
        pn += __shfl_xor(pn, off, 64);
    }
    float zt = 1.0f / (1.0f + expf(-(pz + b_iz[0] + b_hz[0])));
    float nt = tanhf(pn + b_in[0] + b_hn[0]);
    if (l < 48) out[l] = (1.0f - zt) * nt + zt * hidden[l];
}

extern "C" void kernel_launch(void* const* d_in, const int* in_sizes, int n_in,
                              void* d_out, int out_size, void* d_ws, size_t ws_size,
                              hipStream_t stream) {
    const float* loc_agent       = (const float*)d_in[0];
    const float* loc_others      = (const float*)d_in[1];
    const int*   loc_other_index = (const int*)d_in[2];
    const float* feature_img     = (const float*)d_in[3];
    const float* f_vel           = (const float*)d_in[4];
    const float* hiddens         = (const float*)d_in[5];
    const float* hidden          = (const float*)d_in[6];
    const float* W_fc            = (const float*)d_in[7];
    const float* b_fc            = (const float*)d_in[8];
    // d_in[9..12] = weight_ir / weight_hr / bias_ir / bias_hr : dead code
    const float* w_iz            = (const float*)d_in[13];
    const float* w_hz            = (const float*)d_in[14];
    const float* b_iz            = (const float*)d_in[15];
    const float* b_hz            = (const float*)d_in[16];
    const float* w_in            = (const float*)d_in[17];
    const float* w_hn            = (const float*)d_in[18];
    const float* b_in            = (const float*)d_in[19];
    const float* b_hn            = (const float*)d_in[20];

    float*   ws     = (float*)d_ws;
    float*   fsp    = ws + FSP_OFF;
    uint8_t* binrow = (uint8_t*)d_ws + BINROW_OFF_B;
    float*   out    = (float*)d_out;

    int n = in_sizes[2];            // 400000 neighbors
    int nf4 = n * 12;               // hiddens as float4 count
    int nwords = (n + 3) / 4;       // binrow as u32 words

    hipLaunchKernelGGL(init_ws_kernel, dim3(128), dim3(1024), 0, stream,
                       ws, (uint32_t*)binrow, nwords);
    hipLaunchKernelGGL(bin_kernel, dim3((n + 1023) / 1024), dim3(1024), 0, stream,
                       (const float2*)loc_others, loc_agent, loc_other_index,
                       binrow, ws, n);
    hipLaunchKernelGGL(accum_kernel, dim3(512), dim3(1024), 0, stream,
                       (const float4*)hiddens, binrow, ws, nf4);
    hipLaunchKernelGGL(fc_kernel, dim3(48), dim3(256), 0, stream,
                       W_fc, b_fc, ws, fsp);
    hipLaunchKernelGGL(gru_kernel, dim3(1), dim3(64), 0, stream,
                       feature_img, loc_agent, f_vel, fsp, hidden,
                       w_iz, w_hz, b_iz, b_hz, w_in, w_hn, b_in, b_hn, out);
}